// Round 10
// baseline (87.697 us; speedup 1.0000x reference)
//
#include <hip/hip_runtime.h>

// Gated pair-bias attention (AlphaFold-style), MI355X gfx950.
// B=8 S=1024 D=256 H=8 DH=32.
//
// Pipeline:
//   proj_kernel   : qh=(q Wq^T)*norm, sig=sigmoid(q Wg^T + bg), kh=k Wk^T,
//                   vhT = (v Wv^T)^T per (b,h)  [dh][s]               (bf16 in ws)
//   attn_kernel   : flash attention on 32x32x16 MFMAs, swapped operands
//                   (S^T, O^T). P stays IN REGISTERS (sigma-trick: PV B-frag
//                   = in-lane cvt_pk of softmax output; V read with matching
//                   sigma permutation). No P LDS roundtrip. 128-thr blocks.
//   outproj_kernel: out = og Wo^T  (fp32 to d_out)

typedef __attribute__((ext_vector_type(4))) float f32x4;
typedef __attribute__((ext_vector_type(16))) float f32x16;
typedef __attribute__((ext_vector_type(8))) unsigned short u16x8;
typedef __attribute__((ext_vector_type(4))) unsigned short u16x4;
typedef __attribute__((ext_vector_type(8))) __bf16 bf16x8;
typedef __attribute__((ext_vector_type(4))) __bf16 bf16x4;

#define BB 8
#define SS 1024
#define DD 256
#define HH 8
#define DHD 32
#define L2E 1.4426950408889634f

__device__ __forceinline__ float b2f(unsigned short s) {
  unsigned u = ((unsigned)s) << 16;
  return __builtin_bit_cast(float, u);
}
__device__ __forceinline__ f32x4 mfma16(u16x8 a, u16x8 b, f32x4 c) {
  return __builtin_amdgcn_mfma_f32_16x16x32_bf16(
      __builtin_bit_cast(bf16x8, a), __builtin_bit_cast(bf16x8, b), c, 0, 0, 0);
}
__device__ __forceinline__ f32x16 mfma32(u16x8 a, u16x8 b, f32x16 c) {
  return __builtin_amdgcn_mfma_f32_32x32x16_bf16(
      __builtin_bit_cast(bf16x8, a), __builtin_bit_cast(bf16x8, b), c, 0, 0, 0);
}

// async global->LDS, 16B per lane; dest = wave-uniform base + lane*16 (linear).
__device__ __forceinline__ void gload_lds16(const unsigned short* gsrc,
                                            unsigned short* ldst) {
#if __has_builtin(__builtin_amdgcn_global_load_lds)
  __builtin_amdgcn_global_load_lds(
      (const __attribute__((address_space(1))) unsigned int*)gsrc,
      (__attribute__((address_space(3))) unsigned int*)ldst, 16, 0, 0);
#else
  *(u16x8*)ldst = *(const u16x8*)gsrc;
#endif
}

// ---------------------------------------------------------------------------
// Projections: C[8192,256] = A[8192,256] * W[256,256]^T  (einsum bsd,ed->bse)
// grid (128 row-tiles, 4 col-tiles, 4 slots), 256 threads (4 waves).
// Tile 64x64, K-step 32. LDS chunks (16B) XOR-swizzled.
// slot 3 (v) stores TRANSPOSED per (b,h): vhT[((b*H+h)*DH+dh)*S + s].
// ---------------------------------------------------------------------------
__global__ __launch_bounds__(256) void proj_kernel(
    const float* __restrict__ q, const float* __restrict__ k,
    const float* __restrict__ v,
    const float* __restrict__ Wq, const float* __restrict__ Wg,
    const float* __restrict__ Wk, const float* __restrict__ Wv,
    const float* __restrict__ bg,
    unsigned short* __restrict__ qh, unsigned short* __restrict__ kh,
    unsigned short* __restrict__ vhT, unsigned short* __restrict__ sig) {
  const int slot = blockIdx.z;
  const float* A = (slot <= 1) ? q : (slot == 2 ? k : v);
  const float* W = (slot == 0) ? Wq : (slot == 1 ? Wg : (slot == 2 ? Wk : Wv));
  const int row0 = blockIdx.x * 64, col0 = blockIdx.y * 64;
  const int tid = threadIdx.x;
  const int w = tid >> 6, lane = tid & 63, g = lane >> 4, c = lane & 15;
  const int sr = tid >> 2, sc = tid & 3;

  __shared__ alignas(16) unsigned short As[64 * 32];
  __shared__ alignas(16) unsigned short Ws[64 * 32];

  const f32x4 zero = {0.f, 0.f, 0.f, 0.f};
  f32x4 acc[4] = {zero, zero, zero, zero};

  for (int kk = 0; kk < 8; ++kk) {
    __syncthreads();
    {
      const float* ap = A + (size_t)(row0 + sr) * DD + kk * 32 + sc * 8;
      f32x4 f0 = *(const f32x4*)ap;
      f32x4 f1 = *(const f32x4*)(ap + 4);
      bf16x8 a8;
#pragma unroll
      for (int j = 0; j < 4; ++j) { a8[j] = (__bf16)f0[j]; a8[j + 4] = (__bf16)f1[j]; }
      ((u16x8*)As)[sr * 4 + (sc ^ ((sr >> 1) & 3))] = __builtin_bit_cast(u16x8, a8);

      const float* wp = W + (size_t)(col0 + sr) * DD + kk * 32 + sc * 8;
      f32x4 w0 = *(const f32x4*)wp;
      f32x4 w1 = *(const f32x4*)(wp + 4);
      bf16x8 w8;
#pragma unroll
      for (int j = 0; j < 4; ++j) { w8[j] = (__bf16)w0[j]; w8[j + 4] = (__bf16)w1[j]; }
      ((u16x8*)Ws)[sr * 4 + (sc ^ ((sr >> 1) & 3))] = __builtin_bit_cast(u16x8, w8);
    }
    __syncthreads();
    const int arow = 16 * w + c;
    u16x8 af = ((u16x8*)As)[arow * 4 + (g ^ ((arow >> 1) & 3))];
#pragma unroll
    for (int n = 0; n < 4; ++n) {
      const int brow = 16 * n + c;
      u16x8 wf = ((u16x8*)Ws)[brow * 4 + (g ^ ((brow >> 1) & 3))];
      acc[n] = mfma16(af, wf, acc[n]);
    }
  }

  // D layout: row = 4*(lane>>4)+r, col = lane&15 (m89-verified)
  if (slot == 3) {
    const int row_base = row0 + 16 * w + 4 * g;
    const int bb = row_base >> 10;
    const int s0 = row_base & 1023;
#pragma unroll
    for (int n = 0; n < 4; ++n) {
      const int col = col0 + 16 * n + c;
      bf16x4 pv;
#pragma unroll
      for (int r = 0; r < 4; ++r) pv[r] = (__bf16)acc[n][r];
      *(u16x4*)(vhT + (size_t)(bb * 256 + col) * SS + s0) =
          __builtin_bit_cast(u16x4, pv);
    }
  } else {
#pragma unroll
    for (int n = 0; n < 4; ++n) {
#pragma unroll
      for (int r = 0; r < 4; ++r) {
        const int row = row0 + 16 * w + 4 * g + r;
        const int col = col0 + 16 * n + c;
        const size_t idx = (size_t)row * DD + col;
        const float val = acc[n][r];
        if (slot == 0)
          qh[idx] = __builtin_bit_cast(unsigned short,
                        (__bf16)(val * 0.17677669529663687f));  // DH^-0.5
        else if (slot == 1)
          sig[idx] = __builtin_bit_cast(unsigned short,
                         (__bf16)(1.0f / (1.0f + __expf(-(val + bg[col])))));
        else
          kh[idx] = __builtin_bit_cast(unsigned short, (__bf16)val);
      }
    }
  }
}

// ---------------------------------------------------------------------------
// Flash attention, 32x32x16 MFMA, swapped operands, P in registers.
// grid 1024 blocks x 128 threads (2 waves). Wave w owns q rows
// [qt*64 + 32w, +32); lane's q = base + (lane&31), hi = lane>>5.
// XCD swizzle: widx=(bid&7)*128+bid>>3; h=widx>>7 (bias/KV L2-resident).
//
// QK^T (A=K, B=Q): S^T D-layout (m74/m101): q=lane&31,
//   kv row = (reg&3)+8*(reg>>2)+4*hi  -> softmax lane-local per q.
// PV (A=V^T, B=P^T): k-order sigma = D-row order, so B-frag(ks) =
//   cvt_pk(sv regs 8ks..8ks+7) in place; V read with the SAME sigma:
//   lane reads 8B units u1=8t+4ks+hi and u1|2 (kv blocks of 4).
// K LDS [64][32] chunk-swizzle c^=(row&3); V^T LDS [32][64] 8B-unit
// swizzle u^=((row&7)<<1) — both folded into DMA SOURCE (rule #21).
// Bias/mask issued BEFORE the DMA so their waitcnt keeps DMA in flight.
// exp in exp2 domain. One barrier per 64-kv tile.
// ---------------------------------------------------------------------------
__global__ __launch_bounds__(128, 2) void attn_kernel(
    const unsigned short* __restrict__ qh, const unsigned short* __restrict__ kh,
    const unsigned short* __restrict__ vhT, const unsigned short* __restrict__ sig,
    const float* __restrict__ mask, const float* __restrict__ bias,
    unsigned short* __restrict__ og) {
  const int bid = blockIdx.x;
  const int widx = (bid & 7) * 128 + (bid >> 3);
  const int h = widx >> 7, b = (widx >> 4) & 7, qt = widx & 15;
  const int tid = threadIdx.x;
  const int w = tid >> 6, lane = tid & 63;
  const int qc = lane & 31, hi = lane >> 5;

  __shared__ alignas(16) unsigned short KsB[2][64 * 32];  // [kv][dh] swizzled
  __shared__ alignas(16) unsigned short VtB[2][32 * 64];  // [dh][kv] swizzled

  const int qrow = qt * 64 + w * 32 + qc;
  const unsigned short* qp = qh + (size_t)(b * SS + qrow) * DD + h * DHD;
  const u16x8 qf0 = *(const u16x8*)(qp + 8 * hi);         // B-frag ks=0
  const u16x8 qf1 = *(const u16x8*)(qp + 16 + 8 * hi);    // B-frag ks=1

  f32x16 acc = {};
  float m_r = -1e30f, l_r = 0.f;   // per-lane softmax state (16 of 32 kv rows)

  const float* maskb = mask + b * SS;
  const float* biasq = bias + ((size_t)h * SS + qrow) * SS;

  // DMA staging: K 256 + V 256 chunks of 16B per 64-kv tile, 4 per thread.
  auto stage = [&](int buf, int kv0) {
    unsigned short* Kb = KsB[buf];
    unsigned short* Vb = VtB[buf];
#pragma unroll
    for (int i = 0; i < 2; ++i) {
      const int s = i * 128 + tid;
      const int kr = s >> 2, pc = s & 3;       // K: row, phys 16B chunk
      gload_lds16(
          kh + (size_t)(b * SS + kv0 + kr) * DD + h * DHD + (pc ^ (kr & 3)) * 8,
          Kb + s * 8);
      const int vr = s >> 3, pj = s & 7;       // V: row(dh), phys 16B chunk
      const int lu = (2 * pj) ^ ((vr & 7) << 1);  // logical 8B-unit pair start
      gload_lds16(
          vhT + (size_t)((b * HH + h) * DHD + vr) * SS + kv0 + lu * 4,
          Vb + s * 8);
    }
  };

  stage(0, 0);
  __syncthreads();

#pragma unroll 1
  for (int kt = 0; kt < 16; ++kt) {
    const int cur = kt & 1, kv0 = kt * 64;

    // 1. bias + mask loads FIRST (oldest vmcnt -> waiting on them keeps the
    //    DMA issued below in flight). Rows per reg-quad rq: 8rq+4hi+{0..3}.
    f32x4 bm[2][4];
#pragma unroll
    for (int t = 0; t < 2; ++t)
#pragma unroll
      for (int rq = 0; rq < 4; ++rq) {
        const int off = kv0 + 32 * t + 8 * rq + 4 * hi;
        const f32x4 bi = *(const f32x4*)(biasq + off);
        const f32x4 mk = *(const f32x4*)(maskb + off);
        bm[t][rq] = bi + mk;
      }

    // 2. DMA next tile (flies under compute; drained at the barrier)
    if (kt < 15) stage(cur ^ 1, kv0 + 64);

    const unsigned short* Kb = KsB[cur];
    const unsigned short* Vb = VtB[cur];

    // 3. QK^T: 2 sub-tiles of 32 kv, 2 K-steps each (dh 0-15, 16-31)
    f32x16 sv[2];
#pragma unroll
    for (int t = 0; t < 2; ++t) {
      const int kr = 32 * t + qc;   // A-row = kv
      const u16x8 ka = ((const u16x8*)Kb)[kr * 4 + (hi ^ (kr & 3))];
      const u16x8 kb2 = ((const u16x8*)Kb)[kr * 4 + ((2 + hi) ^ (kr & 3))];
      f32x16 z = {};
      z = mfma32(ka, qf0, z);
      sv[t] = mfma32(kb2, qf1, z);
    }

    // 4. + bias + mask
#pragma unroll
    for (int t = 0; t < 2; ++t)
#pragma unroll
      for (int rq = 0; rq < 4; ++rq)
#pragma unroll
        for (int j = 0; j < 4; ++j) sv[t][4 * rq + j] += bm[t][rq][j];

    // 5. defer-max (T13): common path has zero cross-lane ops
    float pm = sv[0][0];
#pragma unroll
    for (int j = 1; j < 16; ++j) pm = fmaxf(pm, sv[0][j]);
#pragma unroll
    for (int j = 0; j < 16; ++j) pm = fmaxf(pm, sv[1][j]);
    if (!__all(pm - m_r <= 8.0f)) {            // fires at kt=0, then ~never
      const float mx = fmaxf(pm, __shfl_xor(pm, 32));
      const float mnew = fmaxf(m_r, mx);
      const float sc = exp2f((m_r - mnew) * L2E);
      l_r *= sc;
      acc = acc * sc;
      m_r = mnew;
    }

    // 6. exp (exp2 domain) + partial l
    const float nm = -m_r * L2E;
    float ps = 0.f;
#pragma unroll
    for (int t = 0; t < 2; ++t)
#pragma unroll
      for (int j = 0; j < 16; ++j) {
        const float p = exp2f(__builtin_fmaf(sv[t][j], L2E, nm));
        sv[t][j] = p;
        ps += p;
      }
    l_r += ps;

    // 7. PV: B-frag = in-lane cvt_pk (sigma = D-row order); V read with sigma
#pragma unroll
    for (int t = 0; t < 2; ++t) {
      bf16x8 p0, p1;
#pragma unroll
      for (int j = 0; j < 8; ++j) {
        p0[j] = (__bf16)sv[t][j];
        p1[j] = (__bf16)sv[t][8 + j];
      }
#pragma unroll
      for (int ks = 0; ks < 2; ++ks) {
        const int u1 = 8 * t + 4 * ks + hi;
        const int sw = (qc & 7) << 1;          // V-row = dh = qc
        const u16x4 va = *(const u16x4*)(Vb + qc * 64 + (u1 ^ sw) * 4);
        const u16x4 vb2 = *(const u16x4*)(Vb + qc * 64 + ((u1 | 2) ^ sw) * 4);
        const u16x8 vf = {va[0], va[1], va[2], va[3],
                          vb2[0], vb2[1], vb2[2], vb2[3]};
        acc = mfma32(vf, __builtin_bit_cast(u16x8, ks == 0 ? p0 : p1), acc);
      }
    }

    __syncthreads();   // all reads of cur done + next DMA drained
  }

  // epilogue: combine l across the q-pair (lane, lane^32), gate, store
  const float lp = l_r + __shfl_xor(l_r, 32);
  const float inv = 1.0f / lp;
#pragma unroll
  for (int rq = 0; rq < 4; ++rq) {
    const int dh0 = 8 * rq + 4 * hi;
    const size_t idx = (size_t)(b * SS + qrow) * DD + h * DHD + dh0;
    const u16x4 sg = *(const u16x4*)(sig + idx);
    bf16x4 ov;
#pragma unroll
    for (int j = 0; j < 4; ++j)
      ov[j] = (__bf16)(acc[4 * rq + j] * inv * b2f(sg[j]));
    *(u16x4*)(og + idx) = __builtin_bit_cast(u16x4, ov);
  }
}

// ---------------------------------------------------------------------------
// Output projection: out[8192,256] = og[8192,256] * Wo[256,256]^T (fp32 out)
// ---------------------------------------------------------------------------
__global__ __launch_bounds__(256) void outproj_kernel(
    const unsigned short* __restrict__ og, const float* __restrict__ Wo,
    float* __restrict__ out) {
  const int row0 = blockIdx.x * 64, col0 = blockIdx.y * 64;
  const int tid = threadIdx.x;
  const int w = tid >> 6, lane = tid & 63, g = lane >> 4, c = lane & 15;
  const int sr = tid >> 2, sc = tid & 3;

  __shared__ alignas(16) unsigned short As[64 * 32];
  __shared__ alignas(16) unsigned short Ws[64 * 32];

  const f32x4 zero = {0.f, 0.f, 0.f, 0.f};
  f32x4 acc[4] = {zero, zero, zero, zero};

  for (int kk = 0; kk < 8; ++kk) {
    __syncthreads();
    {
      const unsigned short* ap = og + (size_t)(row0 + sr) * DD + kk * 32 + sc * 8;
      ((u16x8*)As)[sr * 4 + (sc ^ ((sr >> 1) & 3))] = *(const u16x8*)ap;

      const float* wp = Wo + (size_t)(col0 + sr) * DD + kk * 32 + sc * 8;
      f32x4 w0 = *(const f32x4*)wp;
      f32x4 w1 = *(const f32x4*)(wp + 4);
      bf16x8 w8;
#pragma unroll
      for (int j = 0; j < 4; ++j) { w8[j] = (__bf16)w0[j]; w8[j + 4] = (__bf16)w1[j]; }
      ((u16x8*)Ws)[sr * 4 + (sc ^ ((sr >> 1) & 3))] = __builtin_bit_cast(u16x8, w8);
    }
    __syncthreads();
    const int arow = 16 * w + c;
    u16x8 af = ((u16x8*)As)[arow * 4 + (g ^ ((arow >> 1) & 3))];
#pragma unroll
    for (int n = 0; n < 4; ++n) {
      const int brow = 16 * n + c;
      u16x8 wf = ((u16x8*)Ws)[brow * 4 + (g ^ ((brow >> 1) & 3))];
      acc[n] = mfma16(af, wf, acc[n]);
    }
  }

#pragma unroll
  for (int n = 0; n < 4; ++n) {
#pragma unroll
    for (int r = 0; r < 4; ++r) {
      const int row = row0 + 16 * w + 4 * g + r;
      const int col = col0 + 16 * n + c;
      out[(size_t)row * DD + col] = acc[n][r];
    }
  }
}

extern "C" void kernel_launch(void* const* d_in, const int* in_sizes, int n_in,
                              void* d_out, int out_size, void* d_ws,
                              size_t ws_size, hipStream_t stream) {
  const float* q    = (const float*)d_in[0];
  const float* k    = (const float*)d_in[1];
  const float* v    = (const float*)d_in[2];
  const float* mask = (const float*)d_in[3];
  const float* bias = (const float*)d_in[4];
  const float* Wq   = (const float*)d_in[5];
  const float* Wk   = (const float*)d_in[6];
  const float* Wv   = (const float*)d_in[7];
  const float* Wg   = (const float*)d_in[8];
  const float* bg   = (const float*)d_in[9];
  const float* Wo   = (const float*)d_in[10];
  float* out = (float*)d_out;

  char* ws = (char*)d_ws;
  unsigned short* qh  = (unsigned short*)(ws);               // 4 MB bf16
  unsigned short* kh  = (unsigned short*)(ws + (4u << 20));  // 4 MB
  unsigned short* vhT = (unsigned short*)(ws + (8u << 20));  // 4 MB (transposed)
  unsigned short* sig = (unsigned short*)(ws + (12u << 20)); // 4 MB
  unsigned short* og  = (unsigned short*)(ws + (16u << 20)); // 4 MB

  hipLaunchKernelGGL(proj_kernel, dim3(128, 4, 4), dim3(256), 0, stream,
                     q, k, v, Wq, Wg, Wk, Wv, bg, qh, kh, vhT, sig);
  hipLaunchKernelGGL(attn_kernel, dim3(1024), dim3(128), 0, stream,
                     qh, kh, vhT, sig, mask, bias, og);
  hipLaunchKernelGGL(outproj_kernel, dim3(128, 4), dim3(256), 0, stream,
                     og, Wo, out);
}